// Round 15
// baseline (257.273 us; speedup 1.0000x reference)
//
#include <hip/hip_runtime.h>

// RETRO chunked cross-attention, MI355X bf16 MFMA pipeline. Round 15:
//  - kv_attn: ONE HEAD PER BLOCK (2048 blocks x 256 threads, 4 waves 2Mx2N).
//    GEMM C[256x128] = e_bf[bc] @ [WkT_h | WvT_h]^T, BK=32 depth-2 ring
//    (48KB), attn K/Vt/Q = 74KB static -> 2 blocks/CU. Cross-block overlap
//    hides the per-tile vmcnt+barrier drain (m114 mechanism) that 10
//    schedule variants at 1 block/CU could not.
//  - gemm_bt / prep / epilogues / attention body: r14 (verified).

typedef __attribute__((ext_vector_type(8))) short short8;
typedef __attribute__((ext_vector_type(4))) float f32x4;
typedef unsigned short ushort_t;
typedef unsigned long long u64;

__device__ inline ushort_t f2bf(float f) {
  union { float f; unsigned int u; } v; v.f = f;
  unsigned int u = v.u;
  return (ushort_t)((u + 0x7fffu + ((u >> 16) & 1u)) >> 16);
}
__device__ inline float bf2f(ushort_t s) {
  union { unsigned int u; float f; } v; v.u = ((unsigned int)s) << 16;
  return v.f;
}

__device__ inline void gl_lds16(const void* g, void* l) {
  __builtin_amdgcn_global_load_lds(
      (const __attribute__((address_space(1))) unsigned int*)g,
      (__attribute__((address_space(3))) unsigned int*)l, 16, 0, 0);
}

// ---------------- merged prep: 4x weight transpose | LN | f32->bf16 cast ----
__global__ void prep_kernel(const float* __restrict__ W0, const float* __restrict__ W1,
                            const float* __restrict__ W2, const float* __restrict__ W3,
                            ushort_t* __restrict__ T0, ushort_t* __restrict__ T1,
                            ushort_t* __restrict__ T2, ushort_t* __restrict__ T3,
                            const float* __restrict__ h, const float* __restrict__ lg,
                            const float* __restrict__ lb, ushort_t* __restrict__ hb,
                            const float* __restrict__ e, ushort_t* __restrict__ e_bf) {
  __shared__ float tile[32][33];
  __shared__ float red[8];
  const int blk = blockIdx.x, t = threadIdx.x;

  if (blk < 4096) {
    const int z = blk >> 10, xy = blk & 1023;
    const float* W = (z == 0) ? W0 : (z == 1) ? W1 : (z == 2) ? W2 : W3;
    ushort_t* WT   = (z == 0) ? T0 : (z == 1) ? T1 : (z == 2) ? T2 : T3;
    int k0 = (xy & 31) * 32, n0 = (xy >> 5) * 32;
    int c = t & 31, r = t >> 5;
#pragma unroll
    for (int p = 0; p < 4; p++)
      tile[r + p * 8][c] = W[(size_t)(k0 + r + p * 8) * 1024 + n0 + c];
    __syncthreads();
#pragma unroll
    for (int p = 0; p < 4; p++)
      WT[(size_t)(n0 + r + p * 8) * 1024 + k0 + c] = f2bf(tile[c][r + p * 8]);
    return;
  }
  if (blk < 12288) {
    int row = blk - 4096;            // 0..8191
    int b = row >> 11, jj = row & 2047;
    ushort_t* dst = hb + (size_t)row * 1024;
    if (jj >= 1985) {
      ((unsigned int*)dst)[t] = 0u;
      ((unsigned int*)dst)[t + 256] = 0u;
      return;
    }
    const float* src = h + ((size_t)(b << 11) + jj + 63) * 1024;
    f32x4 x = *(const f32x4*)&src[t * 4];
    float s = x[0] + x[1] + x[2] + x[3];
    float sq = x[0]*x[0] + x[1]*x[1] + x[2]*x[2] + x[3]*x[3];
#pragma unroll
    for (int off = 32; off > 0; off >>= 1) {
      s  += __shfl_xor(s, off);
      sq += __shfl_xor(sq, off);
    }
    if ((t & 63) == 0) { red[(t >> 6) * 2] = s; red[(t >> 6) * 2 + 1] = sq; }
    __syncthreads();
    float sum = red[0] + red[2] + red[4] + red[6];
    float sumsq = red[1] + red[3] + red[5] + red[7];
    float mu = sum * (1.f / 1024.f);
    float var = sumsq * (1.f / 1024.f) - mu * mu;
    float rs = rsqrtf(var + 1e-5f);
    f32x4 gg = *(const f32x4*)&lg[t * 4];
    f32x4 bv = *(const f32x4*)&lb[t * 4];
    ushort_t o0 = f2bf((x[0] - mu) * rs * gg[0] + bv[0]);
    ushort_t o1 = f2bf((x[1] - mu) * rs * gg[1] + bv[1]);
    ushort_t o2 = f2bf((x[2] - mu) * rs * gg[2] + bv[2]);
    ushort_t o3 = f2bf((x[3] - mu) * rs * gg[3] + bv[3]);
    u64 pack = (u64)o0 | ((u64)o1 << 16) | ((u64)o2 << 32) | ((u64)o3 << 48);
    *(u64*)&dst[t * 4] = pack;
    return;
  }
  {
    int i = (blk - 12288) * 256 + t;   // < 4194304
    const f32x4* sp = (const f32x4*)(e + (size_t)i * 8);
    f32x4 a = sp[0], b = sp[1];
    short8 o;
    o[0] = (short)f2bf(a[0]); o[1] = (short)f2bf(a[1]);
    o[2] = (short)f2bf(a[2]); o[3] = (short)f2bf(a[3]);
    o[4] = (short)f2bf(b[0]); o[5] = (short)f2bf(b[1]);
    o[6] = (short)f2bf(b[2]); o[7] = (short)f2bf(b[3]);
    *(short8*)(e_bf + (size_t)i * 8) = o;
  }
}

// ---------------- 128^2 GEMM, BK=64 coarse schedule (r14) -------------------
template <int EPI>
__launch_bounds__(256, 2)
__global__ void gemm_bt(const ushort_t* __restrict__ A, const ushort_t* __restrict__ BT,
                        const float* __restrict__ bias, ushort_t* __restrict__ Cb,
                        float* __restrict__ Cf, const float* __restrict__ resid) {
  const int bid = blockIdx.x;
  if (EPI == 1 && bid >= 512) {   // prologue rows t < 63
    int tt = bid - 512;           // 0..251
    int b = tt / 63, r = tt % 63;
    size_t idx = ((size_t)(b * 2048) + r) * 1024 + threadIdx.x * 4;
    *(f32x4*)&Cf[idx] = *(const f32x4*)&resid[idx];
    return;
  }
  __shared__ __attribute__((aligned(16))) ushort_t lds[32768];  // 2 x (A 16KB + B 16KB)
  const int cpx = 64;
  const int swz = (bid & 7) * cpx + (bid >> 3);
  const int tm = (swz >> 3) * 128, tn = (swz & 7) * 128;
  const int t = threadIdx.x, lane = t & 63, wv = t >> 6;
  const int wm = (wv >> 1) * 64, wn = (wv & 1) * 64;
  const int row16 = lane & 15, g = lane >> 4;

  const ushort_t* Agp[4];
  const ushort_t* Bgp[4];
  int destC[4];
#pragma unroll
  for (int p = 0; p < 4; p++) {
    int c = t + 256 * p;
    int r = c >> 3, s = c & 7;
    int srck = (s ^ (r & 7)) * 8;
    destC[p] = c * 8;
    Agp[p] = A + (size_t)(tm + r) * 1024 + srck;
    Bgp[p] = BT + (size_t)(tn + r) * 1024 + srck;
  }
#define STGBT(T) { ushort_t* L_ = lds + ((T) & 1) * 16384; const int k0_ = (T) * 64; \
    gl_lds16(Agp[0] + k0_, L_ + destC[0]); gl_lds16(Agp[1] + k0_, L_ + destC[1]); \
    gl_lds16(Agp[2] + k0_, L_ + destC[2]); gl_lds16(Agp[3] + k0_, L_ + destC[3]); \
    gl_lds16(Bgp[0] + k0_, L_ + 8192 + destC[0]); gl_lds16(Bgp[1] + k0_, L_ + 8192 + destC[1]); \
    gl_lds16(Bgp[2] + k0_, L_ + 8192 + destC[2]); gl_lds16(Bgp[3] + k0_, L_ + 8192 + destC[3]); }

  int aoffk[2][4], boffk[2][4];
#pragma unroll
  for (int kk2 = 0; kk2 < 2; kk2++) {
#pragma unroll
    for (int m = 0; m < 4; m++) {
      int ra = wm + m * 16 + row16;
      aoffk[kk2][m] = ra * 64 + (((g + 4 * kk2)) ^ (ra & 7)) * 8;
    }
#pragma unroll
    for (int n = 0; n < 4; n++) {
      int rb = wn + n * 16 + row16;
      boffk[kk2][n] = 8192 + rb * 64 + (((g + 4 * kk2)) ^ (rb & 7)) * 8;
    }
  }

  f32x4 acc[4][4] = {};
  STGBT(0);
  for (int T = 0; T < 16; ++T) {
    asm volatile("s_waitcnt vmcnt(0)" ::: "memory");
    __builtin_amdgcn_s_barrier();
    if (T < 15) STGBT(T + 1);
    const ushort_t* Lb = lds + (T & 1) * 16384;
#pragma unroll
    for (int kk2 = 0; kk2 < 2; kk2++) {
      short8 af[4], bfv[4];
#pragma unroll
      for (int n = 0; n < 4; n++) bfv[n] = *(const short8*)&Lb[boffk[kk2][n]];
#pragma unroll
      for (int m = 0; m < 4; m++) af[m] = *(const short8*)&Lb[aoffk[kk2][m]];
      __builtin_amdgcn_s_setprio(1);
#pragma unroll
      for (int m = 0; m < 4; m++)
#pragma unroll
        for (int n = 0; n < 4; n++)
          acc[m][n] = __builtin_amdgcn_mfma_f32_16x16x32_bf16(af[m], bfv[n], acc[m][n], 0, 0, 0);
      __builtin_amdgcn_s_setprio(0);
    }
  }
#undef STGBT

  const int cr = g * 4, cc = row16;
  if (EPI == 0) {
    const int cb = tn + wn;
    float bsv[4];
#pragma unroll
    for (int n = 0; n < 4; n++) bsv[n] = bias[cb + n * 16 + cc];
#pragma unroll
    for (int m = 0; m < 4; m++) {
      int rbase = tm + wm + m * 16 + cr;
#pragma unroll
      for (int j = 0; j < 4; j++) {
        u64 pack = (u64)f2bf(acc[m][0][j] + bsv[0])
                 | ((u64)f2bf(acc[m][1][j] + bsv[1]) << 16)
                 | ((u64)f2bf(acc[m][2][j] + bsv[2]) << 32)
                 | ((u64)f2bf(acc[m][3][j] + bsv[3]) << 48);
        *(u64*)&Cb[(size_t)(rbase + j) * 1024 + cb + cc * 4] = pack;
      }
    }
  } else {
#pragma unroll
    for (int m = 0; m < 4; m++) {
#pragma unroll
      for (int n = 0; n < 4; n++) {
        int col = tn + wn + n * 16 + cc;
        float bsv = bias[col];
#pragma unroll
        for (int j = 0; j < 4; j++) {
          int rg = tm + wm + m * 16 + cr + j;
          float v = acc[m][n][j] + bsv;
          int b = rg >> 11, jj = rg & 2047;
          if (jj < 1985) {
            size_t oi = ((size_t)(b << 11) + jj + 63) * 1024 + col;
            Cf[oi] = v + resid[oi];
          }
        }
      }
    }
  }
}

// ---------------- FUSED: KV projection + attention, 1 head / block ----------
// Block = (b,c) x head h. GEMM C[256x128] = e_bf[bc] @ [WkT_h | WvT_h]^T.
// 4 waves (2M x 2N): wn=0 -> K cols, wn=1 -> V cols. BK=32, depth-2 ring
// (2 x 12288 elems = 48KB). LDS map (elems): ring 0..24576 | K 0..16896 |
// Vt 16896..33792 | Q 33792..37888 (75776 B static -> 2 blocks/CU).
__launch_bounds__(256, 2)
__global__ void kv_attn(const ushort_t* __restrict__ A, const ushort_t* __restrict__ WkvT,
                        const float* __restrict__ bk, const float* __restrict__ bv,
                        const ushort_t* __restrict__ Qb, ushort_t* __restrict__ Ob) {
  __shared__ __attribute__((aligned(16))) ushort_t smem[37888];
  ushort_t* lds = smem;                          // ring 2 x 12288 elems
  const int bid = blockIdx.x;                    // 2048 blocks, %8==0
  const int swz = (bid & 7) * 256 + (bid >> 3);  // XCD chunk swizzle
  const int bc = swz >> 4, h = swz & 15;         // (b,c) tile, head
  const int tm = bc * 256;
  const int t = threadIdx.x, lane = t & 63, wv = t >> 6;   // 4 waves
  const int wm = wv >> 1, wn = wv & 1;
  const int row16 = lane & 15, g = lane >> 4;

  // ---- Q prefetch (region outside ring; drained by first vmcnt(0) gate) ----
  {
    ushort_t* QsH = smem + 33792;
    size_t qbase = ((size_t)bc * 64) * 1024 + h * 64;
    int ch = t, r = ch >> 3, gq = (ch & 7) ^ (r & 7);
    gl_lds16(Qb + qbase + (size_t)r * 1024 + gq * 8, &QsH[ch * 8]);
    ch = t + 256; r = ch >> 3; gq = (ch & 7) ^ (r & 7);
    gl_lds16(Qb + qbase + (size_t)r * 1024 + gq * 8, &QsH[ch * 8]);
  }

  // ---- staging: per tile A = 1024 chunks (4/thread), B = 512 chunks (2/thread)
  const ushort_t* Agp[4];
  int destA[4];
#pragma unroll
  for (int p = 0; p < 4; p++) {
    int c = t + 256 * p;
    int r = c >> 2, s = c & 3;
    int srck = (s ^ ((r >> 1) & 3)) * 8;
    destA[p] = c * 8;
    Agp[p] = A + (size_t)(tm + r) * 1024 + srck;
  }
  const ushort_t* Bgp[2];
  int destB[2];
#pragma unroll
  for (int p = 0; p < 2; p++) {
    int c = t + 256 * p;
    int r = c >> 2, s = c & 3;
    int srck = (s ^ ((r >> 1) & 3)) * 8;
    destB[p] = 8192 + c * 8;
    int grow = (r < 64) ? (h * 64 + r) : (1024 + h * 64 + (r - 64));
    Bgp[p] = WkvT + (size_t)grow * 1024 + srck;
  }
#define STG32(T) { ushort_t* L_ = lds + ((T) & 1) * 12288; const int k0_ = (T) * 32; \
    gl_lds16(Agp[0] + k0_, L_ + destA[0]); gl_lds16(Agp[1] + k0_, L_ + destA[1]); \
    gl_lds16(Agp[2] + k0_, L_ + destA[2]); gl_lds16(Agp[3] + k0_, L_ + destA[3]); \
    gl_lds16(Bgp[0] + k0_, L_ + destB[0]); gl_lds16(Bgp[1] + k0_, L_ + destB[1]); }

  int aoff[8], boff[4];
#pragma unroll
  for (int m = 0; m < 8; m++) {
    int ra = wm * 128 + m * 16 + row16;
    aoff[m] = ra * 32 + (g ^ ((ra >> 1) & 3)) * 8;
  }
#pragma unroll
  for (int n = 0; n < 4; n++) {
    int rb = wn * 64 + n * 16 + row16;
    boff[n] = 8192 + rb * 32 + (g ^ ((rb >> 1) & 3)) * 8;
  }

  f32x4 acc[8][4] = {};
  STG32(0);
  for (int T = 0; T < 32; ++T) {
    asm volatile("s_waitcnt vmcnt(0)" ::: "memory");
    __builtin_amdgcn_s_barrier();
    if (T < 31) STG32(T + 1);
    const ushort_t* Lb = lds + (T & 1) * 12288;
    short8 af[8], bfv[4];
#pragma unroll
    for (int n = 0; n < 4; n++) bfv[n] = *(const short8*)&Lb[boff[n]];
#pragma unroll
    for (int m = 0; m < 8; m++) af[m] = *(const short8*)&Lb[aoff[m]];
    __builtin_amdgcn_s_setprio(1);
#pragma unroll
    for (int m = 0; m < 8; m++)
#pragma unroll
      for (int n = 0; n < 4; n++)
        acc[m][n] = __builtin_amdgcn_mfma_f32_16x16x32_bf16(af[m], bfv[n], acc[m][n], 0, 0, 0);
    __builtin_amdgcn_s_setprio(0);
  }
#undef STG32

  __syncthreads();  // all ring reads done before overlaying K/Vt regions

  // ---- acc -> LDS epilogue ----
  if (wn == 0) {
    // K: bias, pi-packed u64, attention XOR-swizzle
    ushort_t* KsH = smem;
    float bsv[4];
#pragma unroll
    for (int n = 0; n < 4; n++) bsv[n] = bk[h * 64 + n * 16 + row16];
#pragma unroll
    for (int m = 0; m < 8; m++) {
      int krow0 = wm * 128 + m * 16 + g * 4;
#pragma unroll
      for (int j = 0; j < 4; j++) {
        int krow = krow0 + j;
        u64 pack = (u64)f2bf(acc[m][0][j] + bsv[0])
                 | ((u64)f2bf(acc[m][1][j] + bsv[1]) << 16)
                 | ((u64)f2bf(acc[m][2][j] + bsv[2]) << 32)
                 | ((u64)f2bf(acc[m][3][j] + bsv[3]) << 48);
        int sl = ((row16 >> 1) ^ (krow & 7)) * 8 + (row16 & 1) * 4;
        *(u64*)&KsH[krow * 64 + sl] = pack;
      }
    }
  } else {
    // V: bias, transpose (Vt[d][kv], pi^-1 baked: od = n*16+row16)
    ushort_t* VtH = smem + 16896;
    float bsv[4];
#pragma unroll
    for (int n = 0; n < 4; n++) bsv[n] = bv[h * 64 + n * 16 + row16];
#pragma unroll
    for (int m = 0; m < 8; m++) {
      int krow0 = wm * 128 + m * 16 + g * 4;
#pragma unroll
      for (int n = 0; n < 4; n++) {
        int od = n * 16 + row16;
        u64 pack = (u64)f2bf(acc[m][n][0] + bsv[n])
                 | ((u64)f2bf(acc[m][n][1] + bsv[n]) << 16)
                 | ((u64)f2bf(acc[m][n][2] + bsv[n]) << 32)
                 | ((u64)f2bf(acc[m][n][3] + bsv[n]) << 48);
        *(u64*)&VtH[od * 264 + krow0] = pack;
      }
    }
  }
  __syncthreads();

  // ---- attention: 256 threads, one head ----
  ushort_t* QsH = smem + 33792;
  ushort_t* KsH = smem;
  ushort_t* SpH = KsH;   // bf16 S/P [64][264] overlays Ks after QK^T
  ushort_t* VtH = smem + 16896;
  const int wvL = t >> 6, laneL = t & 63;

  const int rowA = laneL & 15, kgA = (laneL >> 4) * 8;
  const int cswz = (rowA & 7) << 3;
  f32x4 accs[4][4] = {};
#pragma unroll
  for (int kk = 0; kk < 64; kk += 32) {
    int cq = ((kk + kgA) ^ cswz);
    short8 af[4], bfr[4];
#pragma unroll
    for (int m = 0; m < 4; m++) af[m] = *(const short8*)&QsH[(m * 16 + rowA) * 64 + cq];
#pragma unroll
    for (int n = 0; n < 4; n++)
      bfr[n] = *(const short8*)&KsH[(wvL * 64 + n * 16 + rowA) * 64 + cq];
#pragma unroll
    for (int m = 0; m < 4; m++)
#pragma unroll
      for (int n = 0; n < 4; n++)
        accs[m][n] = __builtin_amdgcn_mfma_f32_16x16x32_bf16(af[m], bfr[n], accs[m][n], 0, 0, 0);
  }
  __syncthreads();  // Ks reads complete -> safe to overlay with S

  {
    const int cr = (laneL >> 4) * 4, cc = laneL & 15;
#pragma unroll
    for (int m = 0; m < 4; m++)
#pragma unroll
      for (int n = 0; n < 4; n++)
#pragma unroll
        for (int j = 0; j < 4; j++)
          SpH[(m * 16 + cr + j) * 264 + wvL * 64 + n * 16 + cc] = f2bf(accs[m][n][j]);
  }
  __syncthreads();

  {
    const int r = t >> 2, q = t & 3;
    const int base = r * 264 + q * 64;
    float ev[64];
#pragma unroll
    for (int p = 0; p < 8; p++) {
      short8 sv = *(const short8*)&SpH[base + p * 8];
#pragma unroll
      for (int i = 0; i < 8; i++) ev[p * 8 + i] = bf2f((ushort_t)sv[i]);
    }
    float mx = ev[0];
#pragma unroll
    for (int i = 1; i < 64; i++) mx = fmaxf(mx, ev[i]);
    mx = fmaxf(mx, __shfl_xor(mx, 1));
    mx = fmaxf(mx, __shfl_xor(mx, 2));
    float sum = 0.f;
#pragma unroll
    for (int i = 0; i < 64; i++) {
      ev[i] = __expf((ev[i] - mx) * 0.125f);
      sum += ev[i];
    }
    sum += __shfl_xor(sum, 1);
    sum += __shfl_xor(sum, 2);
    float inv = 1.f / sum;
#pragma unroll
    for (int p = 0; p < 8; p++) {
      short8 pv;
#pragma unroll
      for (int i = 0; i < 8; i++) pv[i] = (short)f2bf(ev[p * 8 + i] * inv);
      *(short8*)&SpH[base + p * 8] = pv;
    }
  }
  __syncthreads();

  {
    f32x4 acco[4] = {};
#pragma unroll
    for (int kt = 0; kt < 8; kt++) {
      short8 bfv = *(const short8*)&VtH[(wvL * 16 + rowA) * 264 + kt * 32 + kgA];
#pragma unroll
      for (int m = 0; m < 4; m++) {
        short8 af = *(const short8*)&SpH[(m * 16 + rowA) * 264 + kt * 32 + kgA];
        acco[m] = __builtin_amdgcn_mfma_f32_16x16x32_bf16(af, bfv, acco[m], 0, 0, 0);
      }
    }
    const int cr = (laneL >> 4) * 4, cc = laneL & 15;
    size_t obase = ((size_t)bc * 64) * 1024 + h * 64 + wvL * 16 + cc;
#pragma unroll
    for (int m = 0; m < 4; m++)
#pragma unroll
      for (int j = 0; j < 4; j++)
        Ob[obase + (size_t)(m * 16 + cr + j) * 1024] = f2bf(acco[m][j]);
  }
}

extern "C" void kernel_launch(void* const* d_in, const int* in_sizes, int n_in,
                              void* d_out, int out_size, void* d_ws, size_t ws_size,
                              hipStream_t stream) {
  const float* h    = (const float*)d_in[0];
  const float* e    = (const float*)d_in[1];
  const float* ln_g = (const float*)d_in[2];
  const float* ln_b = (const float*)d_in[3];
  const float* Wq   = (const float*)d_in[4];
  const float* bq   = (const float*)d_in[5];
  const float* Wk   = (const float*)d_in[6];
  const float* bk   = (const float*)d_in[7];
  const float* Wv   = (const float*)d_in[8];
  const float* bv   = (const float*)d_in[9];
  const float* Wo   = (const float*)d_in[10];
  const float* bo   = (const float*)d_in[11];
  float* out = (float*)d_out;

  char* ws = (char*)d_ws;
  const size_t MB = 1024 * 1024;
  ushort_t* WqT  = (ushort_t*)(ws + 0 * MB);
  ushort_t* WkT  = (ushort_t*)(ws + 2 * MB);   // WkT || WvT contiguous
  ushort_t* WvT  = (ushort_t*)(ws + 4 * MB);
  ushort_t* WoT  = (ushort_t*)(ws + 6 * MB);
  ushort_t* hb   = (ushort_t*)(ws + 8 * MB);    // 16 MB
  ushort_t* e_bf = (ushort_t*)(ws + 24 * MB);   // 64 MB
  ushort_t* Qb   = (ushort_t*)(ws + 88 * MB);   // 16 MB
  ushort_t* Obuf = (ushort_t*)(ws + 104 * MB);  // 16 MB -> total 120 MB

  prep_kernel<<<28672, 256, 0, stream>>>(Wq, Wk, Wv, Wo, WqT, WkT, WvT, WoT,
                                         h, ln_g, ln_b, hb, e, e_bf);

  gemm_bt<0><<<512, 256, 0, stream>>>(hb, WqT, bq, Qb, nullptr, nullptr);
  kv_attn<<<2048, 256, 0, stream>>>(e_bf, WkT, bk, bv, Qb, Obuf);

  gemm_bt<1><<<764, 256, 0, stream>>>(Obuf, WoT, bo, nullptr, out, h);
}

// Round 16
// 244.695 us; speedup vs baseline: 1.0514x; 1.0514x over previous
//
#include <hip/hip_runtime.h>

// RETRO chunked cross-attention, MI355X bf16 MFMA pipeline. Round 16:
//  - exact revert to round 14 (best verified total, 249.16 us):
//    * kv_attn: fused KV-proj + attention, 2 heads/block, 512 thr, BK=64,
//      depth-2 ring, 1 vmcnt(0)+barrier per K-tile, Q prefetched outside ring.
//    * gemm_bt: BK=64 coarse ring, pi-packed Q stores / residual O epilogue.
//    * prep: merged transpose+LN+cast.
//  - r15's 1-head occupancy split reverted (neutral-negative: same 8 waves/CU).

typedef __attribute__((ext_vector_type(8))) short short8;
typedef __attribute__((ext_vector_type(4))) float f32x4;
typedef unsigned short ushort_t;
typedef unsigned long long u64;

__device__ inline ushort_t f2bf(float f) {
  union { float f; unsigned int u; } v; v.f = f;
  unsigned int u = v.u;
  return (ushort_t)((u + 0x7fffu + ((u >> 16) & 1u)) >> 16);
}
__device__ inline float bf2f(ushort_t s) {
  union { unsigned int u; float f; } v; v.u = ((unsigned int)s) << 16;
  return v.f;
}

__device__ inline void gl_lds16(const void* g, void* l) {
  __builtin_amdgcn_global_load_lds(
      (const __attribute__((address_space(1))) unsigned int*)g,
      (__attribute__((address_space(3))) unsigned int*)l, 16, 0, 0);
}

// ---------------- merged prep: 4x weight transpose | LN | f32->bf16 cast ----
__global__ void prep_kernel(const float* __restrict__ W0, const float* __restrict__ W1,
                            const float* __restrict__ W2, const float* __restrict__ W3,
                            ushort_t* __restrict__ T0, ushort_t* __restrict__ T1,
                            ushort_t* __restrict__ T2, ushort_t* __restrict__ T3,
                            const float* __restrict__ h, const float* __restrict__ lg,
                            const float* __restrict__ lb, ushort_t* __restrict__ hb,
                            const float* __restrict__ e, ushort_t* __restrict__ e_bf) {
  __shared__ float tile[32][33];
  __shared__ float red[8];
  const int blk = blockIdx.x, t = threadIdx.x;

  if (blk < 4096) {
    const int z = blk >> 10, xy = blk & 1023;
    const float* W = (z == 0) ? W0 : (z == 1) ? W1 : (z == 2) ? W2 : W3;
    ushort_t* WT   = (z == 0) ? T0 : (z == 1) ? T1 : (z == 2) ? T2 : T3;
    int k0 = (xy & 31) * 32, n0 = (xy >> 5) * 32;
    int c = t & 31, r = t >> 5;
#pragma unroll
    for (int p = 0; p < 4; p++)
      tile[r + p * 8][c] = W[(size_t)(k0 + r + p * 8) * 1024 + n0 + c];
    __syncthreads();
#pragma unroll
    for (int p = 0; p < 4; p++)
      WT[(size_t)(n0 + r + p * 8) * 1024 + k0 + c] = f2bf(tile[c][r + p * 8]);
    return;
  }
  if (blk < 12288) {
    int row = blk - 4096;            // 0..8191
    int b = row >> 11, jj = row & 2047;
    ushort_t* dst = hb + (size_t)row * 1024;
    if (jj >= 1985) {
      ((unsigned int*)dst)[t] = 0u;
      ((unsigned int*)dst)[t + 256] = 0u;
      return;
    }
    const float* src = h + ((size_t)(b << 11) + jj + 63) * 1024;
    f32x4 x = *(const f32x4*)&src[t * 4];
    float s = x[0] + x[1] + x[2] + x[3];
    float sq = x[0]*x[0] + x[1]*x[1] + x[2]*x[2] + x[3]*x[3];
#pragma unroll
    for (int off = 32; off > 0; off >>= 1) {
      s  += __shfl_xor(s, off);
      sq += __shfl_xor(sq, off);
    }
    if ((t & 63) == 0) { red[(t >> 6) * 2] = s; red[(t >> 6) * 2 + 1] = sq; }
    __syncthreads();
    float sum = red[0] + red[2] + red[4] + red[6];
    float sumsq = red[1] + red[3] + red[5] + red[7];
    float mu = sum * (1.f / 1024.f);
    float var = sumsq * (1.f / 1024.f) - mu * mu;
    float rs = rsqrtf(var + 1e-5f);
    f32x4 gg = *(const f32x4*)&lg[t * 4];
    f32x4 bv = *(const f32x4*)&lb[t * 4];
    ushort_t o0 = f2bf((x[0] - mu) * rs * gg[0] + bv[0]);
    ushort_t o1 = f2bf((x[1] - mu) * rs * gg[1] + bv[1]);
    ushort_t o2 = f2bf((x[2] - mu) * rs * gg[2] + bv[2]);
    ushort_t o3 = f2bf((x[3] - mu) * rs * gg[3] + bv[3]);
    u64 pack = (u64)o0 | ((u64)o1 << 16) | ((u64)o2 << 32) | ((u64)o3 << 48);
    *(u64*)&dst[t * 4] = pack;
    return;
  }
  {
    int i = (blk - 12288) * 256 + t;   // < 4194304
    const f32x4* sp = (const f32x4*)(e + (size_t)i * 8);
    f32x4 a = sp[0], b = sp[1];
    short8 o;
    o[0] = (short)f2bf(a[0]); o[1] = (short)f2bf(a[1]);
    o[2] = (short)f2bf(a[2]); o[3] = (short)f2bf(a[3]);
    o[4] = (short)f2bf(b[0]); o[5] = (short)f2bf(b[1]);
    o[6] = (short)f2bf(b[2]); o[7] = (short)f2bf(b[3]);
    *(short8*)(e_bf + (size_t)i * 8) = o;
  }
}

// ---------------- 128^2 GEMM, BK=64 coarse schedule (r14) -------------------
// EPI 0: bf16 out, pi-packed 8B stores (Q path), grid 512.
// EPI 1: f32 out + residual + shifted store (O path), grid 764.
template <int EPI>
__launch_bounds__(256, 2)
__global__ void gemm_bt(const ushort_t* __restrict__ A, const ushort_t* __restrict__ BT,
                        const float* __restrict__ bias, ushort_t* __restrict__ Cb,
                        float* __restrict__ Cf, const float* __restrict__ resid) {
  const int bid = blockIdx.x;
  if (EPI == 1 && bid >= 512) {   // prologue rows t < 63
    int tt = bid - 512;           // 0..251
    int b = tt / 63, r = tt % 63;
    size_t idx = ((size_t)(b * 2048) + r) * 1024 + threadIdx.x * 4;
    *(f32x4*)&Cf[idx] = *(const f32x4*)&resid[idx];
    return;
  }
  __shared__ __attribute__((aligned(16))) ushort_t lds[32768];  // 2 x (A 16KB + B 16KB)
  const int cpx = 64;             // 512 GEMM blocks / 8 XCDs
  const int swz = (bid & 7) * cpx + (bid >> 3);
  const int tm = (swz >> 3) * 128, tn = (swz & 7) * 128;
  const int t = threadIdx.x, lane = t & 63, wv = t >> 6;
  const int wm = (wv >> 1) * 64, wn = (wv & 1) * 64;
  const int row16 = lane & 15, g = lane >> 4;

  const ushort_t* Agp[4];
  const ushort_t* Bgp[4];
  int destC[4];
#pragma unroll
  for (int p = 0; p < 4; p++) {
    int c = t + 256 * p;
    int r = c >> 3, s = c & 7;
    int srck = (s ^ (r & 7)) * 8;
    destC[p] = c * 8;
    Agp[p] = A + (size_t)(tm + r) * 1024 + srck;
    Bgp[p] = BT + (size_t)(tn + r) * 1024 + srck;
  }
#define STGBT(T) { ushort_t* L_ = lds + ((T) & 1) * 16384; const int k0_ = (T) * 64; \
    gl_lds16(Agp[0] + k0_, L_ + destC[0]); gl_lds16(Agp[1] + k0_, L_ + destC[1]); \
    gl_lds16(Agp[2] + k0_, L_ + destC[2]); gl_lds16(Agp[3] + k0_, L_ + destC[3]); \
    gl_lds16(Bgp[0] + k0_, L_ + 8192 + destC[0]); gl_lds16(Bgp[1] + k0_, L_ + 8192 + destC[1]); \
    gl_lds16(Bgp[2] + k0_, L_ + 8192 + destC[2]); gl_lds16(Bgp[3] + k0_, L_ + 8192 + destC[3]); }

  int aoffk[2][4], boffk[2][4];
#pragma unroll
  for (int kk2 = 0; kk2 < 2; kk2++) {
#pragma unroll
    for (int m = 0; m < 4; m++) {
      int ra = wm + m * 16 + row16;
      aoffk[kk2][m] = ra * 64 + (((g + 4 * kk2)) ^ (ra & 7)) * 8;
    }
#pragma unroll
    for (int n = 0; n < 4; n++) {
      int rb = wn + n * 16 + row16;
      boffk[kk2][n] = 8192 + rb * 64 + (((g + 4 * kk2)) ^ (rb & 7)) * 8;
    }
  }

  f32x4 acc[4][4] = {};
  STGBT(0);
  for (int T = 0; T < 16; ++T) {
    asm volatile("s_waitcnt vmcnt(0)" ::: "memory");
    __builtin_amdgcn_s_barrier();
    if (T < 15) STGBT(T + 1);
    const ushort_t* Lb = lds + (T & 1) * 16384;
#pragma unroll
    for (int kk2 = 0; kk2 < 2; kk2++) {
      short8 af[4], bfv[4];
#pragma unroll
      for (int n = 0; n < 4; n++) bfv[n] = *(const short8*)&Lb[boffk[kk2][n]];
#pragma unroll
      for (int m = 0; m < 4; m++) af[m] = *(const short8*)&Lb[aoffk[kk2][m]];
      __builtin_amdgcn_s_setprio(1);
#pragma unroll
      for (int m = 0; m < 4; m++)
#pragma unroll
        for (int n = 0; n < 4; n++)
          acc[m][n] = __builtin_amdgcn_mfma_f32_16x16x32_bf16(af[m], bfv[n], acc[m][n], 0, 0, 0);
      __builtin_amdgcn_s_setprio(0);
    }
  }
#undef STGBT

  const int cr = g * 4, cc = row16;
  if (EPI == 0) {
    const int cb = tn + wn;
    float bsv[4];
#pragma unroll
    for (int n = 0; n < 4; n++) bsv[n] = bias[cb + n * 16 + cc];
#pragma unroll
    for (int m = 0; m < 4; m++) {
      int rbase = tm + wm + m * 16 + cr;
#pragma unroll
      for (int j = 0; j < 4; j++) {
        u64 pack = (u64)f2bf(acc[m][0][j] + bsv[0])
                 | ((u64)f2bf(acc[m][1][j] + bsv[1]) << 16)
                 | ((u64)f2bf(acc[m][2][j] + bsv[2]) << 32)
                 | ((u64)f2bf(acc[m][3][j] + bsv[3]) << 48);
        *(u64*)&Cb[(size_t)(rbase + j) * 1024 + cb + cc * 4] = pack;
      }
    }
  } else {
#pragma unroll
    for (int m = 0; m < 4; m++) {
#pragma unroll
      for (int n = 0; n < 4; n++) {
        int col = tn + wn + n * 16 + cc;
        float bsv = bias[col];
#pragma unroll
        for (int j = 0; j < 4; j++) {
          int rg = tm + wm + m * 16 + cr + j;
          float v = acc[m][n][j] + bsv;
          int b = rg >> 11, jj = rg & 2047;
          if (jj < 1985) {
            size_t oi = ((size_t)(b << 11) + jj + 63) * 1024 + col;
            Cf[oi] = v + resid[oi];
          }
        }
      }
    }
  }
}

// ---------------- FUSED: KV projection + attention (r13/r14, BK=64) ---------
__launch_bounds__(512, 2)
__global__ void kv_attn(const ushort_t* __restrict__ A, const ushort_t* __restrict__ WkvT,
                        const float* __restrict__ bk, const float* __restrict__ bv,
                        const ushort_t* __restrict__ Qb, ushort_t* __restrict__ Ob) {
  __shared__ __attribute__((aligned(16))) ushort_t smem[75776];
  ushort_t* lds = smem;                          // ring 2 x 32768 elems
  const int bid = blockIdx.x;                    // 1024 blocks
  const int swz = (bid & 7) * 128 + (bid >> 3);  // XCD chunk swizzle
  const int bc = swz >> 3, hp = swz & 7;
  const int tm = bc * 256;
  const int t = threadIdx.x, lane = t & 63, wv = t >> 6;
  const int wm = wv >> 2, wn = wv & 3;
  const int row16 = lane & 15, g = lane >> 4;

  // ---- Q prefetch (issued first; drained by the first vmcnt(0) gate) ----
  {
    const int hb2q = t >> 8, tlq = t & 255;
    ushort_t* QsH = smem + 67584 + hb2q * 4096;
    size_t qbase = ((size_t)bc * 64) * 1024 + (hp * 2 + hb2q) * 64;
    int ch = tlq, r = ch >> 3, gq = (ch & 7) ^ (r & 7);
    gl_lds16(Qb + qbase + (size_t)r * 1024 + gq * 8, &QsH[ch * 8]);
    ch = tlq + 256; r = ch >> 3; gq = (ch & 7) ^ (r & 7);
    gl_lds16(Qb + qbase + (size_t)r * 1024 + gq * 8, &QsH[ch * 8]);
  }

  // ---- staging geometry: 2048 A-chunks + 2048 B-chunks per tile, 8/thread --
  const ushort_t* Agp[4];
  const ushort_t* Bgp[4];
  int destC[4];
#pragma unroll
  for (int p = 0; p < 4; p++) {
    int c = t + 512 * p;
    int r = c >> 3, s = c & 7;
    int srck = (s ^ (r & 7)) * 8;
    destC[p] = c * 8;
    Agp[p] = A + (size_t)(tm + r) * 1024 + srck;
    int grow = (r < 128) ? (hp * 128 + r) : (1024 + hp * 128 + (r - 128));
    Bgp[p] = WkvT + (size_t)grow * 1024 + srck;
  }
#define STG64(T) { ushort_t* L_ = lds + ((T) & 1) * 32768; const int k0_ = (T) * 64; \
    gl_lds16(Agp[0] + k0_, L_ + destC[0]); gl_lds16(Agp[1] + k0_, L_ + destC[1]); \
    gl_lds16(Agp[2] + k0_, L_ + destC[2]); gl_lds16(Agp[3] + k0_, L_ + destC[3]); \
    gl_lds16(Bgp[0] + k0_, L_ + 16384 + destC[0]); gl_lds16(Bgp[1] + k0_, L_ + 16384 + destC[1]); \
    gl_lds16(Bgp[2] + k0_, L_ + 16384 + destC[2]); gl_lds16(Bgp[3] + k0_, L_ + 16384 + destC[3]); }

  int aoffk[2][8], boffk[2][4];
#pragma unroll
  for (int kk2 = 0; kk2 < 2; kk2++) {
#pragma unroll
    for (int m = 0; m < 8; m++) {
      int ra = wm * 128 + m * 16 + row16;
      aoffk[kk2][m] = ra * 64 + (((g + 4 * kk2)) ^ (ra & 7)) * 8;
    }
#pragma unroll
    for (int n = 0; n < 4; n++) {
      int rb = wn * 64 + n * 16 + row16;
      boffk[kk2][n] = 16384 + rb * 64 + (((g + 4 * kk2)) ^ (rb & 7)) * 8;
    }
  }

  f32x4 acc[8][4] = {};
  STG64(0);
  for (int T = 0; T < 16; ++T) {
    asm volatile("s_waitcnt vmcnt(0)" ::: "memory");
    __builtin_amdgcn_s_barrier();
    if (T < 15) STG64(T + 1);
    const ushort_t* Lb = lds + (T & 1) * 32768;
#pragma unroll
    for (int kk2 = 0; kk2 < 2; kk2++) {
      short8 af[8], bfv[4];
#pragma unroll
      for (int n = 0; n < 4; n++) bfv[n] = *(const short8*)&Lb[boffk[kk2][n]];
#pragma unroll
      for (int m = 0; m < 8; m++) af[m] = *(const short8*)&Lb[aoffk[kk2][m]];
      __builtin_amdgcn_s_setprio(1);
#pragma unroll
      for (int m = 0; m < 8; m++)
#pragma unroll
        for (int n = 0; n < 4; n++)
          acc[m][n] = __builtin_amdgcn_mfma_f32_16x16x32_bf16(af[m], bfv[n], acc[m][n], 0, 0, 0);
      __builtin_amdgcn_s_setprio(0);
    }
  }
#undef STG64

  __syncthreads();  // all ring reads done before overlaying K/Vt regions

  // ---- acc -> LDS epilogue ----
  if (wn < 2) {
    ushort_t* KsH = smem + wn * 16896;
    float bsv[4];
#pragma unroll
    for (int n = 0; n < 4; n++) bsv[n] = bk[hp * 128 + wn * 64 + n * 16 + row16];
#pragma unroll
    for (int m = 0; m < 8; m++) {
      int krow0 = wm * 128 + m * 16 + g * 4;
#pragma unroll
      for (int j = 0; j < 4; j++) {
        int krow = krow0 + j;
        u64 pack = (u64)f2bf(acc[m][0][j] + bsv[0])
                 | ((u64)f2bf(acc[m][1][j] + bsv[1]) << 16)
                 | ((u64)f2bf(acc[m][2][j] + bsv[2]) << 32)
                 | ((u64)f2bf(acc[m][3][j] + bsv[3]) << 48);
        int sl = ((row16 >> 1) ^ (krow & 7)) * 8 + (row16 & 1) * 4;
        *(u64*)&KsH[krow * 64 + sl] = pack;
      }
    }
  } else {
    ushort_t* VtH = smem + 33792 + (wn & 1) * 16896;
    float bsv[4];
#pragma unroll
    for (int n = 0; n < 4; n++) bsv[n] = bv[hp * 128 + (wn - 2) * 64 + n * 16 + row16];
#pragma unroll
    for (int m = 0; m < 8; m++) {
      int krow0 = wm * 128 + m * 16 + g * 4;
#pragma unroll
      for (int n = 0; n < 4; n++) {
        int od = n * 16 + row16;
        u64 pack = (u64)f2bf(acc[m][n][0] + bsv[n])
                 | ((u64)f2bf(acc[m][n][1] + bsv[n]) << 16)
                 | ((u64)f2bf(acc[m][n][2] + bsv[n]) << 32)
                 | ((u64)f2bf(acc[m][n][3] + bsv[n]) << 48);
        *(u64*)&VtH[od * 264 + krow0] = pack;
      }
    }
  }
  __syncthreads();

  // ---- attention: threads [0,256) head A, [256,512) head B ----
  const int tl = t & 255, hb2 = t >> 8;
  const int wvL = tl >> 6, laneL = tl & 63;
  ushort_t* QsH = smem + 67584 + hb2 * 4096;
  ushort_t* KsH = smem + hb2 * 16896;
  ushort_t* SpH = KsH;
  ushort_t* VtH = smem + 33792 + hb2 * 16896;

  const int rowA = laneL & 15, kgA = (laneL >> 4) * 8;
  const int cswz = (rowA & 7) << 3;
  f32x4 accs[4][4] = {};
#pragma unroll
  for (int kk = 0; kk < 64; kk += 32) {
    int cq = ((kk + kgA) ^ cswz);
    short8 af[4], bfr[4];
#pragma unroll
    for (int m = 0; m < 4; m++) af[m] = *(const short8*)&QsH[(m * 16 + rowA) * 64 + cq];
#pragma unroll
    for (int n = 0; n < 4; n++)
      bfr[n] = *(const short8*)&KsH[(wvL * 64 + n * 16 + rowA) * 64 + cq];
#pragma unroll
    for (int m = 0; m < 4; m++)
#pragma unroll
      for (int n = 0; n < 4; n++)
        accs[m][n] = __builtin_amdgcn_mfma_f32_16x16x32_bf16(af[m], bfr[n], accs[m][n], 0, 0, 0);
  }
  __syncthreads();

  {
    const int cr = (laneL >> 4) * 4, cc = laneL & 15;
#pragma unroll
    for (int m = 0; m < 4; m++)
#pragma unroll
      for (int n = 0; n < 4; n++)
#pragma unroll
        for (int j = 0; j < 4; j++)
          SpH[(m * 16 + cr + j) * 264 + wvL * 64 + n * 16 + cc] = f2bf(accs[m][n][j]);
  }
  __syncthreads();

  {
    const int r = tl >> 2, q = tl & 3;
    const int base = r * 264 + q * 64;
    float ev[64];
#pragma unroll
    for (int p = 0; p < 8; p++) {
      short8 sv = *(const short8*)&SpH[base + p * 8];
#pragma unroll
      for (int i = 0; i < 8; i++) ev[p * 8 + i] = bf2f((ushort_t)sv[i]);
    }
    float mx = ev[0];
#pragma unroll
    for (int i = 1; i < 64; i++) mx = fmaxf(mx, ev[i]);
    mx = fmaxf(mx, __shfl_xor(mx, 1));
    mx = fmaxf(mx, __shfl_xor(mx, 2));
    float sum = 0.f;
#pragma unroll
    for (int i = 0; i < 64; i++) {
      ev[i] = __expf((ev[i] - mx) * 0.125f);
      sum += ev[i];
    }
    sum += __shfl_xor(sum, 1);
    sum += __shfl_xor(sum, 2);
    float inv = 1.f / sum;
#pragma unroll
    for (int p = 0; p < 8; p++) {
      short8 pv;
#pragma unroll
      for (int i = 0; i < 8; i++) pv[i] = (short)f2bf(ev[p * 8 + i] * inv);
      *(short8*)&SpH[base + p * 8] = pv;
    }
  }
  __syncthreads();

  {
    f32x4 acco[4] = {};
#pragma unroll
    for (int kt = 0; kt < 8; kt++) {
      short8 bfv = *(const short8*)&VtH[(wvL * 16 + rowA) * 264 + kt * 32 + kgA];
#pragma unroll
      for (int m = 0; m < 4; m++) {
        short8 af = *(const short8*)&SpH[(m * 16 + rowA) * 264 + kt * 32 + kgA];
        acco[m] = __builtin_amdgcn_mfma_f32_16x16x32_bf16(af, bfv, acco[m], 0, 0, 0);
      }
    }
    const int cr = (laneL >> 4) * 4, cc = laneL & 15;
    size_t obase = ((size_t)bc * 64) * 1024 + (hp * 2 + hb2) * 64 + wvL * 16 + cc;
#pragma unroll
    for (int m = 0; m < 4; m++)
#pragma unroll
      for (int j = 0; j < 4; j++)
        Ob[obase + (size_t)(m * 16 + cr + j) * 1024] = f2bf(acco[m][j]);
  }
}

extern "C" void kernel_launch(void* const* d_in, const int* in_sizes, int n_in,
                              void* d_out, int out_size, void* d_ws, size_t ws_size,
                              hipStream_t stream) {
  const float* h    = (const float*)d_in[0];
  const float* e    = (const float*)d_in[1];
  const float* ln_g = (const float*)d_in[2];
  const float* ln_b = (const float*)d_in[3];
  const float* Wq   = (const float*)d_in[4];
  const float* bq   = (const float*)d_in[5];
  const float* Wk   = (const float*)d_in[6];
  const float* bk   = (const float*)d_in[7];
  const float* Wv   = (const float*)d_in[8];
  const float* bv   = (const float*)d_in[9];
  const float* Wo   = (const float*)d_in[10];
  const float* bo   = (const float*)d_in[11];
  float* out = (float*)d_out;

  char* ws = (char*)d_ws;
  const size_t MB = 1024 * 1024;
  ushort_t* WqT  = (ushort_t*)(ws + 0 * MB);
  ushort_t* WkT  = (ushort_t*)(ws + 2 * MB);   // WkT || WvT contiguous
  ushort_t* WvT  = (ushort_t*)(ws + 4 * MB);
  ushort_t* WoT  = (ushort_t*)(ws + 6 * MB);
  ushort_t* hb   = (ushort_t*)(ws + 8 * MB);    // 16 MB
  ushort_t* e_bf = (ushort_t*)(ws + 24 * MB);   // 64 MB
  ushort_t* Qb   = (ushort_t*)(ws + 88 * MB);   // 16 MB
  ushort_t* Obuf = (ushort_t*)(ws + 104 * MB);  // 16 MB -> total 120 MB

  prep_kernel<<<28672, 256, 0, stream>>>(Wq, Wk, Wv, Wo, WqT, WkT, WvT, WoT,
                                         h, ln_g, ln_b, hb, e, e_bf);

  gemm_bt<0><<<512, 256, 0, stream>>>(hb, WqT, bq, Qb, nullptr, nullptr);
  kv_attn<<<1024, 512, 0, stream>>>(e_bf, WkT, bk, bv, Qb, Obuf);

  gemm_bt<1><<<764, 256, 0, stream>>>(Obuf, WoT, bo, nullptr, out, h);
}